// Round 9
// baseline (1147.346 us; speedup 1.0000x reference)
//
#include <hip/hip_runtime.h>

#define N_NODES 256
#define COND    64
#define E_PAIRS 32640
#define OUTCOLS 65280
#define BATCH   512
#define SLOTS   576    // 9 row-tiles of 64 (big rows padded to 64, then small, then pad)
#define D1      256
#define D2      512
#define D3      1024

typedef __attribute__((ext_vector_type(8))) short bf16x8;   // MFMA A/B frag (4 VGPR)
typedef __attribute__((ext_vector_type(4))) float f32x4;    // MFMA C/D frag
typedef __attribute__((ext_vector_type(4))) unsigned int u32x4;

static __device__ __forceinline__ unsigned short f2bf(float f) {   // RNE float->bf16
    unsigned int u = __float_as_uint(f);
    u += 0x7FFF + ((u >> 16) & 1);
    return (unsigned short)(u >> 16);
}
static __device__ __forceinline__ float bf2f(unsigned short h) {
    return __uint_as_float(((unsigned int)h) << 16);
}

// ---------------- kernel 0: ballot-based stable sort into 64-aligned slots ---
__global__ void k0_sort(const float* __restrict__ x, int* __restrict__ meta,
                        int* __restrict__ borig) {
    __shared__ int wc[9];
    int t = threadIdx.x;                 // blockDim = 576 (9 waves)
    if (t < SLOTS) borig[t] = -1;        // pad default
    int m = 0;
    if (t < BATCH) m = (x[t * COND] > 0.0f) ? 1 : 0;
    unsigned long long bm = __ballot(m);
    int wave = t >> 6;
    int lane = t & 63;
    int lanePre = __popcll(bm & ((1ull << lane) - 1ull));
    if (lane == 0) wc[wave] = __popcll(bm);
    __syncthreads();
    int nbig = 0, preBig = 0;
    #pragma unroll
    for (int w = 0; w < 8; ++w) {        // waves 0..7 cover t<512
        int c = wc[w];
        if (w < wave) preBig += c;
        nbig += c;
    }
    int S = (nbig + 63) & ~63;           // big slots [0,S), small [S, S+nsmall)
    if (t < BATCH) {
        int onesBefore = preBig + lanePre;
        int slot = m ? onesBefore : (S + (t - onesBefore));
        borig[slot] = t;
    }
    if (t == 0) meta[0] = S;
}

// ---------------- kernel 1: MLP layers as tiled GEMMs ------------------------
// 64x64 tile, 256 threads, 4x4 per thread, ReLU fused.
// GATHER (layer 0): rows via borig. SPLIT (layer 2): write h as 3 bf16 limbs
// DIRECTLY IN MFMA A-FRAGMENT LANE ORDER (hbA) so k2 loads coalesced frags.
template <bool GATHER, int K, int DOUT, bool SPLIT>
__global__ __launch_bounds__(256) void k1_gemm(
    const float* __restrict__ in,
    const float* __restrict__ wbig, const float* __restrict__ bbig,
    const float* __restrict__ wsml, const float* __restrict__ bsml,
    const int* __restrict__ meta, const int* __restrict__ borig,
    float* __restrict__ out, unsigned short* __restrict__ hbA) {
    __shared__ float hs[16][64 + 4];     // transposed act tile
    __shared__ float wt[16][64 + 4];     // weight tile
    int tid = threadIdx.x;
    int by = blockIdx.x;                 // row tile 0..8
    int bx = blockIdx.y;                 // col tile
    int r0 = by * 64;
    int cb = bx * 64;
    int S = meta[0];
    bool big = (r0 < S);                 // row tiles are expert-uniform
    const float* w = big ? wbig : wsml;
    const float* bias = big ? bbig : bsml;

    int lm = tid >> 2;                   // act-load row 0..63
    int lq = tid & 3;                    // act-load k quad
    int wk = tid >> 4;                   // w-load k row 0..15
    int wc = (tid & 15) * 4;             // w-load col offset

    int tm = tid >> 4;                   // 0..15 : rows tm*4..+3
    int tn = tid & 15;                   // 0..15 : cols tn*4..+3

    const float* hrow;
    if (GATHER) {
        int b = borig[r0 + lm];
        hrow = (b >= 0) ? &in[(size_t)b * K] : (const float*)0;
    } else {
        hrow = &in[(size_t)(r0 + lm) * K];   // pad rows: defined (relu of bias chain)
    }

    float acc[4][4];
    #pragma unroll
    for (int i = 0; i < 4; ++i)
        #pragma unroll
        for (int j = 0; j < 4; ++j) acc[i][j] = 0.f;

    for (int k0 = 0; k0 < K; k0 += 16) {
        float4 hv = make_float4(0.f, 0.f, 0.f, 0.f);
        if (!GATHER || hrow) hv = *(const float4*)&hrow[k0 + lq * 4];
        float4 wv = *(const float4*)&w[(size_t)(k0 + wk) * DOUT + cb + wc];
        __syncthreads();
        hs[lq * 4 + 0][lm] = hv.x;
        hs[lq * 4 + 1][lm] = hv.y;
        hs[lq * 4 + 2][lm] = hv.z;
        hs[lq * 4 + 3][lm] = hv.w;
        *(float4*)&wt[wk][wc] = wv;
        __syncthreads();
        #pragma unroll
        for (int kk = 0; kk < 16; ++kk) {
            float4 a  = *(const float4*)&hs[kk][tm * 4];
            float4 bf = *(const float4*)&wt[kk][tn * 4];
            acc[0][0] = fmaf(a.x, bf.x, acc[0][0]);
            acc[0][1] = fmaf(a.x, bf.y, acc[0][1]);
            acc[0][2] = fmaf(a.x, bf.z, acc[0][2]);
            acc[0][3] = fmaf(a.x, bf.w, acc[0][3]);
            acc[1][0] = fmaf(a.y, bf.x, acc[1][0]);
            acc[1][1] = fmaf(a.y, bf.y, acc[1][1]);
            acc[1][2] = fmaf(a.y, bf.z, acc[1][2]);
            acc[1][3] = fmaf(a.y, bf.w, acc[1][3]);
            acc[2][0] = fmaf(a.z, bf.x, acc[2][0]);
            acc[2][1] = fmaf(a.z, bf.y, acc[2][1]);
            acc[2][2] = fmaf(a.z, bf.z, acc[2][2]);
            acc[2][3] = fmaf(a.z, bf.w, acc[2][3]);
            acc[3][0] = fmaf(a.w, bf.x, acc[3][0]);
            acc[3][1] = fmaf(a.w, bf.y, acc[3][1]);
            acc[3][2] = fmaf(a.w, bf.z, acc[3][2]);
            acc[3][3] = fmaf(a.w, bf.w, acc[3][3]);
        }
    }

    float4 bv = *(const float4*)&bias[cb + tn * 4];
    #pragma unroll
    for (int i = 0; i < 4; ++i) {
        float o[4];
        o[0] = fmaxf(acc[i][0] + bv.x, 0.f);
        o[1] = fmaxf(acc[i][1] + bv.y, 0.f);
        o[2] = fmaxf(acc[i][2] + bv.z, 0.f);
        o[3] = fmaxf(acc[i][3] + bv.w, 0.f);
        if (SPLIT) {
            // element (row, k): frag addr = ((by*32+kk)*3+limb)*2048 + m*512
            //                               + (lg*16 + l15)*8 + j   [shorts]
            int row = r0 + tm * 4 + i;
            int by_ = row >> 6, rl = row & 63;
            int mfr = rl >> 4, p15 = rl & 15;
            int kt  = cb + tn * 4;           // 4 consecutive k, same lg group
            int kk  = kt >> 5, lgk = (kt >> 3) & 3, j0 = kt & 7;
            size_t base = (size_t)(by_ * 32 + kk) * 6144 + (size_t)mfr * 512
                        + (size_t)(lgk * 16 + p15) * 8 + j0;
            ushort4 s0, s1, s2;
            unsigned short* q0[4] = {&s0.x, &s0.y, &s0.z, &s0.w};
            unsigned short* q1[4] = {&s1.x, &s1.y, &s1.z, &s1.w};
            unsigned short* q2[4] = {&s2.x, &s2.y, &s2.z, &s2.w};
            #pragma unroll
            for (int j = 0; j < 4; ++j) {
                unsigned short a0 = f2bf(o[j]);
                float r1v = o[j] - bf2f(a0);
                unsigned short a1 = f2bf(r1v);
                float r2v = r1v - bf2f(a1);
                *q0[j] = a0; *q1[j] = a1; *q2[j] = f2bf(r2v);
            }
            *(ushort4*)&hbA[base]        = s0;
            *(ushort4*)&hbA[base + 2048] = s1;
            *(ushort4*)&hbA[base + 4096] = s2;
        } else {
            float4 ov;
            ov.x = o[0]; ov.y = o[1]; ov.z = o[2]; ov.w = o[3];
            *(float4*)&out[(size_t)(r0 + tm * 4 + i) * DOUT + cb + tn * 4] = ov;
        }
    }
}

// ---------------- kernel 2: bf16x3 MFMA DIFF-GEMM, G=3 fused rows ------------
// R6/R8 lessons: (1) 6 sequential MFMAs into one acc = dependency-stalled
// matrix pipe; (2) per-(by,bx) blocks re-split the same w3 cols 9x; (3) LDS
// dbuf kills occupancy. This version: block = (row-GROUP of 3 by's) x (64 diff
// cols); split B once per step, feed 3 row-tiles (72 MFMA per split); MFMAs
// ordered TERM-MAJOR across the 4 independent m-accumulators (dep distance 4).
// Zero LDS, zero barriers, 3 waves/SIMD. Grid 1536: unit = xcd*192 + s ->
// XCD owns contiguous col-tiles; 3 row-groups of a col-tile adjacent -> w3
// fetched from HBM once, shared in that XCD's L2 (R4-proven mechanism).
__global__ __launch_bounds__(256) void k2_mfma(
    const unsigned short* __restrict__ hbA,
    const float* __restrict__ bw3, const float* __restrict__ bb3,
    const float* __restrict__ sw3, const float* __restrict__ sb3,
    const float* __restrict__ gum,
    const int* __restrict__ meta, const int* __restrict__ borig,
    unsigned char* __restrict__ bits) {
    int tid = threadIdx.x;
    int wgid = blockIdx.x;              // 0..1535
    int r8   = wgid & 7;                // XCD slot (consecutive wgid round-robin)
    int s_   = wgid >> 3;               // 0..191
    int unit = r8 * 192 + s_;           // XCD r8 owns units [192*r8, 192*r8+192)
    if (unit >= 1530) return;           // 6 pad blocks (no barriers -> safe)
    int c = unit / 3;                   // col-tile 0..509 (64 diff cols)
    int g = unit % 3;                   // row group 0..2 (by = 3g..3g+2)

    int lane = tid & 63;
    int wid  = tid >> 6;                // wave 0..3 -> 16 cols each
    int l15  = lane & 15;
    int lg   = lane >> 4;               // k-group 0..3

    int colg = c * 64 + wid * 16 + l15; // this lane's diff column
    int S    = meta[0];
    int nbt  = S >> 6;                  // number of big row-tiles
    int by0  = 3 * g;
    bool big0 = (by0     < nbt);
    bool big1 = (by0 + 1 < nbt);
    bool big2 = (by0 + 2 < nbt);
    bool needB = big0;                  // flags are monotone: big first
    bool needS = !big2;

    f32x4 acc[3][4];
    #pragma unroll
    for (int i = 0; i < 3; ++i)
        #pragma unroll
        for (int m = 0; m < 4; ++m) acc[i][m] = (f32x4)0.f;

    bf16x8 Bb0 = {}, Bb1 = {}, Bb2 = {};   // big-expert diff limbs
    bf16x8 Bs0 = {}, Bs1 = {}, Bs2 = {};   // small-expert diff limbs

    const float* wbp = bw3 + 2 * (size_t)colg;   // + k*OUTCOLS
    const float* wsp = sw3 + 2 * (size_t)colg;
    const unsigned short* apbase = hbA + (size_t)lane * 8;

// load 8 raw diffs (k = lg*8 + 0..7 of current K-tile) and split to 3 limbs
#define SPLIT8(B0, B1, B2, WP) do {                                             \
    u32x4 f0_, f1_, f2_;                                                        \
    _Pragma("unroll")                                                           \
    for (int p_ = 0; p_ < 4; ++p_) {                                            \
        float2 pA_ = *(const float2*)((WP) + (size_t)(2 * p_) * OUTCOLS);       \
        float2 pB_ = *(const float2*)((WP) + (size_t)(2 * p_ + 1) * OUTCOLS);   \
        float dA_ = pA_.x - pA_.y, dB_ = pB_.x - pB_.y;                         \
        unsigned short aL_ = f2bf(dA_), aH_ = f2bf(dB_);                        \
        f0_[p_] = (unsigned)aL_ | ((unsigned)aH_ << 16);                        \
        float rA_ = dA_ - bf2f(aL_), rB_ = dB_ - bf2f(aH_);                     \
        unsigned short bL_ = f2bf(rA_), bH_ = f2bf(rB_);                        \
        f1_[p_] = (unsigned)bL_ | ((unsigned)bH_ << 16);                        \
        float sA_ = rA_ - bf2f(bL_), sB_ = rB_ - bf2f(bH_);                     \
        f2_[p_] = (unsigned)f2bf(sA_) | ((unsigned)f2bf(sB_) << 16);            \
    }                                                                           \
    B0 = __builtin_bit_cast(bf16x8, f0_);                                       \
    B1 = __builtin_bit_cast(bf16x8, f1_);                                       \
    B2 = __builtin_bit_cast(bf16x8, f2_);                                       \
} while (0)

// 24 MFMA for row-tile group-member I, TERM-MAJOR over m (dep distance 4):
// terms h0w0, h0w1, h1w0, h1w1, h0w2, h2w0 (bf16^3 fp32 emulation, proven)
#define MMBODY(I, B0, B1, B2) do {                                              \
    _Pragma("unroll") for (int m_ = 0; m_ < 4; ++m_)                            \
        acc[I][m_] = __builtin_amdgcn_mfma_f32_16x16x32_bf16(af_[0][m_], B0, acc[I][m_], 0, 0, 0); \
    _Pragma("unroll") for (int m_ = 0; m_ < 4; ++m_)                            \
        acc[I][m_] = __builtin_amdgcn_mfma_f32_16x16x32_bf16(af_[0][m_], B1, acc[I][m_], 0, 0, 0); \
    _Pragma("unroll") for (int m_ = 0; m_ < 4; ++m_)                            \
        acc[I][m_] = __builtin_amdgcn_mfma_f32_16x16x32_bf16(af_[1][m_], B0, acc[I][m_], 0, 0, 0); \
    _Pragma("unroll") for (int m_ = 0; m_ < 4; ++m_)                            \
        acc[I][m_] = __builtin_amdgcn_mfma_f32_16x16x32_bf16(af_[1][m_], B1, acc[I][m_], 0, 0, 0); \
    _Pragma("unroll") for (int m_ = 0; m_ < 4; ++m_)                            \
        acc[I][m_] = __builtin_amdgcn_mfma_f32_16x16x32_bf16(af_[0][m_], B2, acc[I][m_], 0, 0, 0); \
    _Pragma("unroll") for (int m_ = 0; m_ < 4; ++m_)                            \
        acc[I][m_] = __builtin_amdgcn_mfma_f32_16x16x32_bf16(af_[2][m_], B0, acc[I][m_], 0, 0, 0); \
} while (0)

#define MM(I, ISBIG) do {                                                       \
    const unsigned short* ap_ = apbase + (size_t)((by0 + (I)) * 32 + t) * 6144; \
    bf16x8 af_[3][4];                                                           \
    _Pragma("unroll") for (int l_ = 0; l_ < 3; ++l_)                            \
        _Pragma("unroll") for (int m_ = 0; m_ < 4; ++m_)                        \
            af_[l_][m_] = *(const bf16x8*)(ap_ + l_ * 2048 + m_ * 512);         \
    if (ISBIG) { MMBODY(I, Bb0, Bb1, Bb2); }                                    \
    else       { MMBODY(I, Bs0, Bs1, Bs2); }                                    \
} while (0)

    for (int t = 0; t < 32; ++t) {
        size_t krow = (size_t)(t * 32 + lg * 8) * OUTCOLS;
        if (needB) SPLIT8(Bb0, Bb1, Bb2, wbp + krow);
        if (needS) SPLIT8(Bs0, Bs1, Bs2, wsp + krow);
        MM(0, big0);
        MM(1, big1);
        MM(2, big2);
    }
#undef SPLIT8
#undef MMBODY
#undef MM

    // ---- epilogue: bias-diff + gumbel-diff, compare, store bit bytes ----
    float2 bvB = *(const float2*)&bb3[2 * colg];
    float2 bvS = *(const float2*)&sb3[2 * colg];
    float bdB = bvB.x - bvB.y;
    float bdS = bvS.x - bvS.y;
    #pragma unroll
    for (int i = 0; i < 3; ++i) {
        int by = by0 + i;
        float bd = (by < nbt) ? bdB : bdS;
        #pragma unroll
        for (int m = 0; m < 4; ++m) {
            #pragma unroll
            for (int r = 0; r < 4; ++r) {
                int slot = by * 64 + m * 16 + lg * 4 + r;
                int b = borig[slot];
                if (b < 0) continue;
                float2 gv = *(const float2*)&gum[(size_t)b * OUTCOLS + 2 * colg];
                float gval = acc[i][m][r] + bd + (gv.x - gv.y);
                bits[(size_t)b * E_PAIRS + colg] = (gval >= 0.f) ? 1 : 0;
            }
        }
    }
}

// ---------------- kernel 3: tiled bit->fp32 expansion with LDS transpose ------
__global__ __launch_bounds__(256) void k3_expand(
    const unsigned char* __restrict__ bits, float* __restrict__ out) {
    __shared__ unsigned char L[64][68];   // stride 68 bytes
    const int ti_tab[10] = {0,0,0,0,1,1,1,2,2,3};
    const int tj_tab[10] = {0,1,2,3,1,2,3,2,3,3};
    int p = blockIdx.x;                   // 0..9
    int b = blockIdx.y;                   // 0..511
    int ti = ti_tab[p], tj = tj_tab[p];
    int t = threadIdx.x;

    // ---- stage bits: row r (i = ti*64+r), 16 bytes per thread ----
    {
        int r = t >> 2;                   // 0..63
        int q = t & 3;                    // 0..3
        int i = ti * 64 + r;
        // e(i,j) = i*(511-i)/2 + j - i - 1  (valid for j > i)
        long base = (long)b * E_PAIRS + (long)i * (511 - i) / 2 - i - 1;
        int j0 = tj * 64 + q * 16;
        #pragma unroll
        for (int k = 0; k < 16; ++k) {
            int j = j0 + k;
            unsigned char v = (j > i) ? bits[base + j] : (unsigned char)0;
            L[r][q * 16 + k] = v;
        }
    }
    __syncthreads();

    int h  = t >> 4;                      // 0..15  (row within group of 16)
    int w4 = (t & 15) * 4;                // col base, float4 granularity

    // ---- direct tile: out[b][ti*64+ii][tj*64 + w4 .. +3] ----
    {
        #pragma unroll
        for (int rr = 0; rr < 4; ++rr) {
            int ii = rr * 16 + h;
            int i_ = ti * 64 + ii;
            float4 v;
            if (ti == tj) {
                int jj;
                jj = w4 + 0; v.x = (jj > ii) ? (float)L[ii][jj] : (jj < ii ? (float)L[jj][ii] : 0.f);
                jj = w4 + 1; v.y = (jj > ii) ? (float)L[ii][jj] : (jj < ii ? (float)L[jj][ii] : 0.f);
                jj = w4 + 2; v.z = (jj > ii) ? (float)L[ii][jj] : (jj < ii ? (float)L[jj][ii] : 0.f);
                jj = w4 + 3; v.w = (jj > ii) ? (float)L[ii][jj] : (jj < ii ? (float)L[jj][ii] : 0.f);
            } else {
                v.x = (float)L[ii][w4 + 0];
                v.y = (float)L[ii][w4 + 1];
                v.z = (float)L[ii][w4 + 2];
                v.w = (float)L[ii][w4 + 3];
            }
            size_t o = (((size_t)b * 256 + i_) * 256) + tj * 64 + w4;
            *(float4*)&out[o] = v;
        }
    }

    // ---- mirrored tile (off-diagonal only): out[b][tj*64+jj][ti*64 + w4 ..] ----
    if (ti != tj) {
        #pragma unroll
        for (int rr = 0; rr < 4; ++rr) {
            int jj = rr * 16 + h;
            int j_ = tj * 64 + jj;
            float4 v;                      // value(i=col, j=row) = L[col_local][jj]
            v.x = (float)L[w4 + 0][jj];
            v.y = (float)L[w4 + 1][jj];
            v.z = (float)L[w4 + 2][jj];
            v.w = (float)L[w4 + 3][jj];
            size_t o = (((size_t)b * 256 + j_) * 256) + ti * 64 + w4;
            *(float4*)&out[o] = v;
        }
    }
}

// -----------------------------------------------------------------------------
extern "C" void kernel_launch(void* const* d_in, const int* in_sizes, int n_in,
                              void* d_out, int out_size, void* d_ws, size_t ws_size,
                              hipStream_t stream) {
    const float* x   = (const float*)d_in[0];
    const float* gum = (const float*)d_in[1];
    const float* bw0 = (const float*)d_in[2];  const float* bb0 = (const float*)d_in[3];
    const float* sw0 = (const float*)d_in[4];  const float* sb0 = (const float*)d_in[5];
    const float* bw1 = (const float*)d_in[6];  const float* bb1 = (const float*)d_in[7];
    const float* sw1 = (const float*)d_in[8];  const float* sb1 = (const float*)d_in[9];
    const float* bw2 = (const float*)d_in[10]; const float* bb2 = (const float*)d_in[11];
    const float* sw2 = (const float*)d_in[12]; const float* sb2 = (const float*)d_in[13];
    const float* bw3 = (const float*)d_in[14]; const float* bb3 = (const float*)d_in[15];
    const float* sw3 = (const float*)d_in[16]; const float* sb3 = (const float*)d_in[17];

    char* ws = (char*)d_ws;
    int*   meta  = (int*)ws;                               // 64 B
    int*   borig = (int*)(ws + 64);                        // 576 ints
    float* act1  = (float*)(ws + 4096);                    // 576*256 fp32
    float* act2  = (float*)(ws + 593920);                  // 576*512 fp32
    unsigned short* hbA = (unsigned short*)(ws + 1773568); // 576*1024*3 bf16 frag-order
    unsigned char* bits = (unsigned char*)(ws + 5312512);  // 512*32640 bytes
    float* out = (float*)d_out;                            // total ws use ~22.0 MB

    k0_sort<<<1, SLOTS, 0, stream>>>(x, meta, borig);
    k1_gemm<true,  COND, D1, false><<<dim3(9, D1 / 64), 256, 0, stream>>>(
        x,    bw0, bb0, sw0, sb0, meta, borig, act1, 0);
    k1_gemm<false, D1,   D2, false><<<dim3(9, D2 / 64), 256, 0, stream>>>(
        act1, bw1, bb1, sw1, sb1, meta, borig, act2, 0);
    k1_gemm<false, D2,   D3, true><<<dim3(9, D3 / 64), 256, 0, stream>>>(
        act2, bw2, bb2, sw2, sb2, meta, borig, (float*)0, hbA);
    k2_mfma<<<1536, 256, 0, stream>>>(hbA, bw3, bb3, sw3, sb3, gum,
                                      meta, borig, bits);
    k3_expand<<<dim3(10, BATCH), 256, 0, stream>>>(bits, out);
}

// Round 10
// 1028.345 us; speedup vs baseline: 1.1157x; 1.1157x over previous
//
#include <hip/hip_runtime.h>

#define N_NODES 256
#define COND    64
#define E_PAIRS 32640
#define OUTCOLS 65280
#define BATCH   512
#define SLOTS   576    // 9 row-tiles of 64 (big rows padded to 64, then small, then pad)
#define D1      256
#define D2      512
#define D3      1024

typedef __attribute__((ext_vector_type(8))) short bf16x8;   // MFMA A/B frag (4 VGPR)
typedef __attribute__((ext_vector_type(4))) float f32x4;    // MFMA C/D frag
typedef __attribute__((ext_vector_type(4))) unsigned int u32x4;

static __device__ __forceinline__ unsigned short f2bf(float f) {   // RNE float->bf16
    unsigned int u = __float_as_uint(f);
    u += 0x7FFF + ((u >> 16) & 1);
    return (unsigned short)(u >> 16);
}
static __device__ __forceinline__ float bf2f(unsigned short h) {
    return __uint_as_float(((unsigned int)h) << 16);
}

// ---------------- kernel 0: ballot-based stable sort into 64-aligned slots ---
__global__ void k0_sort(const float* __restrict__ x, int* __restrict__ meta,
                        int* __restrict__ borig) {
    __shared__ int wc[9];
    int t = threadIdx.x;                 // blockDim = 576 (9 waves)
    if (t < SLOTS) borig[t] = -1;        // pad default
    int m = 0;
    if (t < BATCH) m = (x[t * COND] > 0.0f) ? 1 : 0;
    unsigned long long bm = __ballot(m);
    int wave = t >> 6;
    int lane = t & 63;
    int lanePre = __popcll(bm & ((1ull << lane) - 1ull));
    if (lane == 0) wc[wave] = __popcll(bm);
    __syncthreads();
    int nbig = 0, preBig = 0;
    #pragma unroll
    for (int w = 0; w < 8; ++w) {        // waves 0..7 cover t<512
        int c = wc[w];
        if (w < wave) preBig += c;
        nbig += c;
    }
    int S = (nbig + 63) & ~63;           // big slots [0,S), small [S, S+nsmall)
    if (t < BATCH) {
        int onesBefore = preBig + lanePre;
        int slot = m ? onesBefore : (S + (t - onesBefore));
        borig[slot] = t;
    }
    if (t == 0) meta[0] = S;
}

// ---------------- kernel 1: MLP layers as tiled GEMMs ------------------------
// 64x64 tile, 256 threads, 4x4 per thread, ReLU fused.
// GATHER (layer 0): rows via borig. SPLIT (layer 2): write h as 3 bf16 limbs
// DIRECTLY IN MFMA A-FRAGMENT LANE ORDER (hbA) so k2 loads coalesced frags.
template <bool GATHER, int K, int DOUT, bool SPLIT>
__global__ __launch_bounds__(256) void k1_gemm(
    const float* __restrict__ in,
    const float* __restrict__ wbig, const float* __restrict__ bbig,
    const float* __restrict__ wsml, const float* __restrict__ bsml,
    const int* __restrict__ meta, const int* __restrict__ borig,
    float* __restrict__ out, unsigned short* __restrict__ hbA) {
    __shared__ float hs[16][64 + 4];     // transposed act tile
    __shared__ float wt[16][64 + 4];     // weight tile
    int tid = threadIdx.x;
    int by = blockIdx.x;                 // row tile 0..8
    int bx = blockIdx.y;                 // col tile
    int r0 = by * 64;
    int cb = bx * 64;
    int S = meta[0];
    bool big = (r0 < S);                 // row tiles are expert-uniform
    const float* w = big ? wbig : wsml;
    const float* bias = big ? bbig : bsml;

    int lm = tid >> 2;                   // act-load row 0..63
    int lq = tid & 3;                    // act-load k quad
    int wk = tid >> 4;                   // w-load k row 0..15
    int wc = (tid & 15) * 4;             // w-load col offset

    int tm = tid >> 4;                   // 0..15 : rows tm*4..+3
    int tn = tid & 15;                   // 0..15 : cols tn*4..+3

    const float* hrow;
    if (GATHER) {
        int b = borig[r0 + lm];
        hrow = (b >= 0) ? &in[(size_t)b * K] : (const float*)0;
    } else {
        hrow = &in[(size_t)(r0 + lm) * K];   // pad rows hold garbage; harmless
    }

    float acc[4][4];
    #pragma unroll
    for (int i = 0; i < 4; ++i)
        #pragma unroll
        for (int j = 0; j < 4; ++j) acc[i][j] = 0.f;

    for (int k0 = 0; k0 < K; k0 += 16) {
        float4 hv = make_float4(0.f, 0.f, 0.f, 0.f);
        if (!GATHER || hrow) hv = *(const float4*)&hrow[k0 + lq * 4];
        float4 wv = *(const float4*)&w[(size_t)(k0 + wk) * DOUT + cb + wc];
        __syncthreads();
        hs[lq * 4 + 0][lm] = hv.x;
        hs[lq * 4 + 1][lm] = hv.y;
        hs[lq * 4 + 2][lm] = hv.z;
        hs[lq * 4 + 3][lm] = hv.w;
        *(float4*)&wt[wk][wc] = wv;
        __syncthreads();
        #pragma unroll
        for (int kk = 0; kk < 16; ++kk) {
            float4 a  = *(const float4*)&hs[kk][tm * 4];
            float4 bf = *(const float4*)&wt[kk][tn * 4];
            acc[0][0] = fmaf(a.x, bf.x, acc[0][0]);
            acc[0][1] = fmaf(a.x, bf.y, acc[0][1]);
            acc[0][2] = fmaf(a.x, bf.z, acc[0][2]);
            acc[0][3] = fmaf(a.x, bf.w, acc[0][3]);
            acc[1][0] = fmaf(a.y, bf.x, acc[1][0]);
            acc[1][1] = fmaf(a.y, bf.y, acc[1][1]);
            acc[1][2] = fmaf(a.y, bf.z, acc[1][2]);
            acc[1][3] = fmaf(a.y, bf.w, acc[1][3]);
            acc[2][0] = fmaf(a.z, bf.x, acc[2][0]);
            acc[2][1] = fmaf(a.z, bf.y, acc[2][1]);
            acc[2][2] = fmaf(a.z, bf.z, acc[2][2]);
            acc[2][3] = fmaf(a.z, bf.w, acc[2][3]);
            acc[3][0] = fmaf(a.w, bf.x, acc[3][0]);
            acc[3][1] = fmaf(a.w, bf.y, acc[3][1]);
            acc[3][2] = fmaf(a.w, bf.z, acc[3][2]);
            acc[3][3] = fmaf(a.w, bf.w, acc[3][3]);
        }
    }

    float4 bv = *(const float4*)&bias[cb + tn * 4];
    #pragma unroll
    for (int i = 0; i < 4; ++i) {
        float o[4];
        o[0] = fmaxf(acc[i][0] + bv.x, 0.f);
        o[1] = fmaxf(acc[i][1] + bv.y, 0.f);
        o[2] = fmaxf(acc[i][2] + bv.z, 0.f);
        o[3] = fmaxf(acc[i][3] + bv.w, 0.f);
        if (SPLIT) {
            // element (row, k): frag addr = ((by*32+kk)*3+limb)*2048 + m*512
            //                               + (lg*16 + l15)*8 + j   [shorts]
            int row = r0 + tm * 4 + i;
            int by_ = row >> 6, rl = row & 63;
            int mfr = rl >> 4, p15 = rl & 15;
            int kt  = cb + tn * 4;           // 4 consecutive k, same lg group
            int kk  = kt >> 5, lgk = (kt >> 3) & 3, j0 = kt & 7;
            size_t base = (size_t)(by_ * 32 + kk) * 6144 + (size_t)mfr * 512
                        + (size_t)(lgk * 16 + p15) * 8 + j0;
            ushort4 s0, s1, s2;
            unsigned short* q0[4] = {&s0.x, &s0.y, &s0.z, &s0.w};
            unsigned short* q1[4] = {&s1.x, &s1.y, &s1.z, &s1.w};
            unsigned short* q2[4] = {&s2.x, &s2.y, &s2.z, &s2.w};
            #pragma unroll
            for (int j = 0; j < 4; ++j) {
                unsigned short a0 = f2bf(o[j]);
                float r1v = o[j] - bf2f(a0);
                unsigned short a1 = f2bf(r1v);
                float r2v = r1v - bf2f(a1);
                *q0[j] = a0; *q1[j] = a1; *q2[j] = f2bf(r2v);
            }
            *(ushort4*)&hbA[base]        = s0;
            *(ushort4*)&hbA[base + 2048] = s1;
            *(ushort4*)&hbA[base + 4096] = s2;
        } else {
            float4 ov;
            ov.x = o[0]; ov.y = o[1]; ov.z = o[2]; ov.w = o[3];
            *(float4*)&out[(size_t)(r0 + tm * 4 + i) * DOUT + cb + tn * 4] = ov;
        }
    }
}

// ---------------- kernel 2: bf16x3 MFMA DIFF-GEMM, fence-pinned 2-deep pipe --
// R7 failure autopsy: compiler SANK the prefetch loads back to their uses
// (VGPR 72 vs ~160 required by two live buffers) -> full latency exposed.
// Fix: asm volatile memory fences after each LOADB pin load-issue order
// (loads cannot cross a "memory" clobber); the compiler's own counted
// s_waitcnt then lands at first use, one full STEP (~1500 cy) later.
// Structure otherwise identical to R7 (zero LDS, zero barriers, XCD grid).
__global__ __launch_bounds__(256, 2) void k2_mfma(
    const unsigned short* __restrict__ hbA,
    const float* __restrict__ bw3, const float* __restrict__ bb3,
    const float* __restrict__ sw3, const float* __restrict__ sb3,
    const float* __restrict__ gum,
    const int* __restrict__ meta, const int* __restrict__ borig,
    unsigned char* __restrict__ bits) {
    int tid = threadIdx.x;
    int wgid = blockIdx.x;              // 0..2303
    int xr  = wgid & 7;
    int s_  = wgid >> 3;
    int by  = s_ % 9;                   // row tile 0..8
    int q   = s_ / 9;                   // col chunk 0..31
    int bx  = q * 8 + xr;               // col tile 0..255 (XCD-local col ownership)
    if (bx >= 255) return;              // no barriers -> early exit trivially safe

    int r0 = by * 64;
    int db = bx * 128;                  // diff (e-pair) column base
    int S = meta[0];
    bool big = (r0 < S);
    const float* w3 = big ? bw3 : sw3;
    const float* b3 = big ? bb3 : sb3;

    int lane = tid & 63;
    int wid  = tid >> 6;                // wave 0..3 -> diff cols wid*32..+31
    int l15  = lane & 15;
    int lg   = lane >> 4;               // k-group 0..3

    int colg0 = db + wid * 32 + l15;    // this lane's n=0 diff column

    f32x4 acc[4][2];
    #pragma unroll
    for (int m = 0; m < 4; ++m)
        #pragma unroll
        for (int n = 0; n < 2; ++n) acc[m][n] = (f32x4)0.f;

    const unsigned short* ap0 = hbA + (size_t)(by * 32) * 6144 + (size_t)lane * 8;
    const float* wbase = w3 + (size_t)(lg * 8) * OUTCOLS + 2 * (size_t)colg0;

#define LOADB(BUF, KK) do {                                                     \
    const float* wp_ = wbase + (size_t)(KK) * 32 * OUTCOLS;                     \
    _Pragma("unroll")                                                           \
    for (int n_ = 0; n_ < 2; ++n_) {                                            \
        _Pragma("unroll")                                                       \
        for (int j_ = 0; j_ < 8; ++j_)                                          \
            BUF[n_ * 8 + j_] = *(const float2*)(wp_ + (size_t)j_ * OUTCOLS      \
                                                + n_ * 32);                     \
    }                                                                           \
} while (0)

#define STEP(BUF, KK) do {                                                      \
    const unsigned short* ap_ = ap0 + (size_t)(KK) * 6144;                      \
    bf16x8 af_[3][4];                                                           \
    _Pragma("unroll")                                                           \
    for (int l_ = 0; l_ < 3; ++l_)                                              \
        _Pragma("unroll")                                                       \
        for (int m_ = 0; m_ < 4; ++m_)                                          \
            af_[l_][m_] = *(const bf16x8*)(ap_ + l_ * 2048 + m_ * 512);         \
    _Pragma("unroll")                                                           \
    for (int n_ = 0; n_ < 2; ++n_) {                                            \
        u32x4 f0_, f1_, f2_;                                                    \
        _Pragma("unroll")                                                       \
        for (int w_ = 0; w_ < 4; ++w_) {                                        \
            float dA_ = BUF[n_ * 8 + 2 * w_].x     - BUF[n_ * 8 + 2 * w_].y;    \
            float dB_ = BUF[n_ * 8 + 2 * w_ + 1].x - BUF[n_ * 8 + 2 * w_ + 1].y;\
            unsigned short aL_ = f2bf(dA_), aH_ = f2bf(dB_);                    \
            f0_[w_] = (unsigned int)aL_ | ((unsigned int)aH_ << 16);            \
            float rA_ = dA_ - bf2f(aL_), rB_ = dB_ - bf2f(aH_);                 \
            unsigned short bL_ = f2bf(rA_), bH_ = f2bf(rB_);                    \
            f1_[w_] = (unsigned int)bL_ | ((unsigned int)bH_ << 16);            \
            float sA_ = rA_ - bf2f(bL_), sB_ = rB_ - bf2f(bH_);                 \
            f2_[w_] = (unsigned int)f2bf(sA_) | ((unsigned int)f2bf(sB_) << 16);\
        }                                                                       \
        bf16x8 b0_ = __builtin_bit_cast(bf16x8, f0_);                           \
        bf16x8 b1_ = __builtin_bit_cast(bf16x8, f1_);                           \
        bf16x8 b2_ = __builtin_bit_cast(bf16x8, f2_);                           \
        _Pragma("unroll")                                                       \
        for (int m_ = 0; m_ < 4; ++m_) {                                        \
            f32x4 c_ = acc[m_][n_];                                             \
            c_ = __builtin_amdgcn_mfma_f32_16x16x32_bf16(af_[0][m_], b0_, c_, 0, 0, 0); \
            c_ = __builtin_amdgcn_mfma_f32_16x16x32_bf16(af_[0][m_], b1_, c_, 0, 0, 0); \
            c_ = __builtin_amdgcn_mfma_f32_16x16x32_bf16(af_[1][m_], b0_, c_, 0, 0, 0); \
            c_ = __builtin_amdgcn_mfma_f32_16x16x32_bf16(af_[1][m_], b1_, c_, 0, 0, 0); \
            c_ = __builtin_amdgcn_mfma_f32_16x16x32_bf16(af_[0][m_], b2_, c_, 0, 0, 0); \
            c_ = __builtin_amdgcn_mfma_f32_16x16x32_bf16(af_[2][m_], b0_, c_, 0, 0, 0); \
            acc[m_][n_] = c_;                                                   \
        }                                                                       \
    }                                                                           \
} while (0)

    float2 brE[16], brO[16];
    LOADB(brE, 0);
    asm volatile("" ::: "memory");      // pin: brE(0) issued before loop body
    for (int ki = 0; ki < 16; ++ki) {
        int ke = ki * 2;
        LOADB(brO, ke + 1);             // prefetch odd step
        asm volatile("" ::: "memory");  // loads above cannot sink below this
        STEP(brE, ke);                  // ~1500 cy: brO latency hides here
        LOADB(brE, (ki < 15) ? ke + 2 : 31);   // prefetch next even step
        asm volatile("" ::: "memory");
        STEP(brO, ke + 1);              // brE(next) latency hides here
    }
#undef LOADB
#undef STEP

    // ---- epilogue: bias-diff + gumbel-diff, compare, store bit bytes ----
    #pragma unroll
    for (int n = 0; n < 2; ++n) {
        int colg = db + wid * 32 + n * 16 + l15;     // global e-pair index
        float2 bv = *(const float2*)&b3[2 * colg];
        float bd = bv.x - bv.y;
        #pragma unroll
        for (int m = 0; m < 4; ++m) {
            #pragma unroll
            for (int r = 0; r < 4; ++r) {
                int slot = r0 + m * 16 + lg * 4 + r;
                int b = borig[slot];
                if (b < 0) continue;
                float2 gv = *(const float2*)&gum[(size_t)b * OUTCOLS + 2 * colg];
                float g = acc[m][n][r] + bd + (gv.x - gv.y);
                bits[(size_t)b * E_PAIRS + colg] = (g >= 0.f) ? 1 : 0;
            }
        }
    }
}

// ---------------- kernel 3: tiled bit->fp32 expansion with LDS transpose ------
// (ti,tj) from blockIdx via uniform arithmetic (runtime-indexed const arrays
// can land in per-thread scratch -- rule #20).
__global__ __launch_bounds__(256) void k3_expand(
    const unsigned char* __restrict__ bits, float* __restrict__ out) {
    __shared__ unsigned char L[64][68];   // stride 68 bytes
    int p = blockIdx.x;                   // 0..9 -> (ti,tj), ti<=tj
    int ti = (p >= 4) + (p >= 7) + (p >= 9);
    int off = (ti == 0) ? 0 : (ti == 1) ? 4 : (ti == 2) ? 7 : 9;
    int tj = ti + (p - off);
    int b = blockIdx.y;                   // 0..511
    int t = threadIdx.x;

    // ---- stage bits: row r (i = ti*64+r), 16 bytes per thread ----
    {
        int r = t >> 2;                   // 0..63
        int q = t & 3;                    // 0..3
        int i = ti * 64 + r;
        // e(i,j) = i*(511-i)/2 + j - i - 1  (valid for j > i)
        long base = (long)b * E_PAIRS + (long)i * (511 - i) / 2 - i - 1;
        int j0 = tj * 64 + q * 16;
        #pragma unroll
        for (int k = 0; k < 16; ++k) {
            int j = j0 + k;
            unsigned char v = (j > i) ? bits[base + j] : (unsigned char)0;
            L[r][q * 16 + k] = v;
        }
    }
    __syncthreads();

    int h  = t >> 4;                      // 0..15  (row within group of 16)
    int w4 = (t & 15) * 4;                // col base, float4 granularity

    // ---- direct tile: out[b][ti*64+ii][tj*64 + w4 .. +3] ----
    {
        #pragma unroll
        for (int rr = 0; rr < 4; ++rr) {
            int ii = rr * 16 + h;
            int i_ = ti * 64 + ii;
            float4 v;
            if (ti == tj) {
                int jj;
                jj = w4 + 0; v.x = (jj > ii) ? (float)L[ii][jj] : (jj < ii ? (float)L[jj][ii] : 0.f);
                jj = w4 + 1; v.y = (jj > ii) ? (float)L[ii][jj] : (jj < ii ? (float)L[jj][ii] : 0.f);
                jj = w4 + 2; v.z = (jj > ii) ? (float)L[ii][jj] : (jj < ii ? (float)L[jj][ii] : 0.f);
                jj = w4 + 3; v.w = (jj > ii) ? (float)L[ii][jj] : (jj < ii ? (float)L[jj][ii] : 0.f);
            } else {
                v.x = (float)L[ii][w4 + 0];
                v.y = (float)L[ii][w4 + 1];
                v.z = (float)L[ii][w4 + 2];
                v.w = (float)L[ii][w4 + 3];
            }
            size_t o = (((size_t)b * 256 + i_) * 256) + tj * 64 + w4;
            *(float4*)&out[o] = v;
        }
    }

    // ---- mirrored tile (off-diagonal only): out[b][tj*64+jj][ti*64 + w4 ..] ----
    if (ti != tj) {
        #pragma unroll
        for (int rr = 0; rr < 4; ++rr) {
            int jj = rr * 16 + h;
            int j_ = tj * 64 + jj;
            float4 v;                      // value(i=col, j=row) = L[col_local][jj]
            v.x = (float)L[w4 + 0][jj];
            v.y = (float)L[w4 + 1][jj];
            v.z = (float)L[w4 + 2][jj];
            v.w = (float)L[w4 + 3][jj];
            size_t o = (((size_t)b * 256 + j_) * 256) + ti * 64 + w4;
            *(float4*)&out[o] = v;
        }
    }
}

// -----------------------------------------------------------------------------
extern "C" void kernel_launch(void* const* d_in, const int* in_sizes, int n_in,
                              void* d_out, int out_size, void* d_ws, size_t ws_size,
                              hipStream_t stream) {
    const float* x   = (const float*)d_in[0];
    const float* gum = (const float*)d_in[1];
    const float* bw0 = (const float*)d_in[2];  const float* bb0 = (const float*)d_in[3];
    const float* sw0 = (const float*)d_in[4];  const float* sb0 = (const float*)d_in[5];
    const float* bw1 = (const float*)d_in[6];  const float* bb1 = (const float*)d_in[7];
    const float* sw1 = (const float*)d_in[8];  const float* sb1 = (const float*)d_in[9];
    const float* bw2 = (const float*)d_in[10]; const float* bb2 = (const float*)d_in[11];
    const float* sw2 = (const float*)d_in[12]; const float* sb2 = (const float*)d_in[13];
    const float* bw3 = (const float*)d_in[14]; const float* bb3 = (const float*)d_in[15];
    const float* sw3 = (const float*)d_in[16]; const float* sb3 = (const float*)d_in[17];

    char* ws = (char*)d_ws;
    int*   meta  = (int*)ws;                               // 64 B
    int*   borig = (int*)(ws + 64);                        // 576 ints
    float* act1  = (float*)(ws + 4096);                    // 576*256 fp32
    float* act2  = (float*)(ws + 593920);                  // 576*512 fp32
    unsigned short* hbA = (unsigned short*)(ws + 1773568); // 576*1024*3 bf16 frag-order
    unsigned char* bits = (unsigned char*)(ws + 5312512);  // 512*32640 bytes
    float* out = (float*)d_out;                            // total ws use ~22.0 MB

    k0_sort<<<1, SLOTS, 0, stream>>>(x, meta, borig);
    k1_gemm<true,  COND, D1, false><<<dim3(9, D1 / 64), 256, 0, stream>>>(
        x,    bw0, bb0, sw0, sb0, meta, borig, act1, 0);
    k1_gemm<false, D1,   D2, false><<<dim3(9, D2 / 64), 256, 0, stream>>>(
        act1, bw1, bb1, sw1, sb1, meta, borig, act2, 0);
    k1_gemm<false, D2,   D3, true><<<dim3(9, D3 / 64), 256, 0, stream>>>(
        act2, bw2, bb2, sw2, sb2, meta, borig, (float*)0, hbA);
    k2_mfma<<<2304, 256, 0, stream>>>(hbA, bw3, bb3, sw3, sb3, gum,
                                      meta, borig, bits);
    k3_expand<<<dim3(10, BATCH), 256, 0, stream>>>(bits, out);
}